// Round 9
// baseline (295.692 us; speedup 1.0000x reference)
//
#include <hip/hip_runtime.h>
#include <math.h>

#define N_ 128
#define I_ 256
#define O_ 256
#define P_ 16
#define OT 4      // o's per block (site kernel)
#define IT 8      // i's per block (site kernel)
#define ICH 4     // fallback kernel chunking
#define SQRT_2PI 2.5066282746310002f
#define INV_SQRT_2PI 0.3989422804014327f

// Record: 18 chunks of 64B per pair, 16 pairs interleaved per group.
// chunk c of pair q at byte: (q>>4)*18432 + c*1024 + (q&15)*64
//  chunks 0..15 : column m of M=L^-1 (rows 0..15; zeros above diag; diag =
//                 1/L[mm]). Column 15 rows0,1 stash l2, s^2*l (never FMA'd:
//                 c0=3 skips chunks 0..2 for m=15).
//  chunk 16 : z (16 floats), chunk 17 : w = Q^-1 h.
#define GSTR 4608   // floats per 16-pair group (18*256)
#define NEED_BYTES ((size_t)65536 * 1152)

#define TRI(r, c) ((r) * ((r) + 1) / 2 + (c))

typedef float f2 __attribute__((ext_vector_type(2)));

__device__ __forceinline__ float fast_tanh(float x) {
    const float e2 = __expf(2.0f * x);
    return 1.0f - 2.0f / (e2 + 1.0f);
}

// ============================ Kernel 1: pairs ==============================
// ONE THREAD PER PAIR. 65536 threads = 1024 waves. Whole triangle in regs,
// sequential Cholesky + in-place inversion + w. Zero cross-lane ops.
__global__ __launch_bounds__(64, 1) void gp_pairs(
    const float* __restrict__ z_param, const float* __restrict__ h,
    const float* __restrict__ l_param, const float* __restrict__ s_param,
    const float* __restrict__ jitter_param, float* __restrict__ ws)
{
    const int q = blockIdx.x * 64 + threadIdx.x;   // pair index = i*256 + o
    const int io = q;

    const float l   = __expf(l_param[io]) + 0.2f;
    const float s   = __expf(s_param[io]) + 0.1f;
    const float jit = __expf(jitter_param[io]) + 0.01f;
    const float l2 = l * l;
    const float ninv2l2 = -0.5f / l2;
    const float cQ = INV_SQRT_2PI / l;
    const float noise = jit * jit / (s * s * l * SQRT_2PI);
    const float s2l = s * s * l;

    float zv[P_], hv[P_];
    {
        const float4* zp = (const float4*)(z_param + (size_t)io * P_);
        const float4* hp = (const float4*)(h + (size_t)io * P_);
        #pragma unroll
        for (int c = 0; c < 4; ++c) {
            const float4 z4 = zp[c], h4 = hp[c];
            zv[4*c+0] = z4.x; zv[4*c+1] = z4.y; zv[4*c+2] = z4.z; zv[4*c+3] = z4.w;
            hv[4*c+0] = h4.x; hv[4*c+1] = h4.y; hv[4*c+2] = h4.z; hv[4*c+3] = h4.w;
        }
    }
    #pragma unroll
    for (int p = 0; p < P_; ++p) zv[p] = fast_tanh(zv[p]);

    float A[136];
    #pragma unroll
    for (int r = 0; r < P_; ++r) {
        #pragma unroll
        for (int c = 0; c <= r; ++c) {
            const float d = zv[r] - zv[c];
            A[TRI(r, c)] = cQ * __expf(d * d * ninv2l2) + ((r == c) ? noise : 0.f);
        }
    }

    float dinv[P_];
    #pragma unroll
    for (int k = 0; k < P_; ++k) {
        const float Lkk = sqrtf(A[TRI(k, k)]);
        const float ik = 1.0f / Lkk;
        dinv[k] = ik;
        A[TRI(k, k)] = Lkk;
        #pragma unroll
        for (int r = k + 1; r < P_; ++r) A[TRI(r, k)] *= ik;
        #pragma unroll
        for (int c = k + 1; c < P_; ++c) {
            const float Lck = A[TRI(c, k)];
            #pragma unroll
            for (int r = c; r < P_; ++r) A[TRI(r, c)] -= A[TRI(r, k)] * Lck;
        }
    }

    #pragma unroll
    for (int j = 0; j < P_; ++j) {
        #pragma unroll
        for (int r = j + 1; r < P_; ++r) {
            float acc = A[TRI(r, j)] * dinv[j];
            #pragma unroll
            for (int k = j + 1; k < r; ++k) acc += A[TRI(r, k)] * A[TRI(k, j)];
            A[TRI(r, j)] = -dinv[r] * acc;
        }
        A[TRI(j, j)] = dinv[j];
    }

    float tv[P_], wv[P_];
    #pragma unroll
    for (int r = 0; r < P_; ++r) {
        float acc = 0.f;
        #pragma unroll
        for (int c = 0; c <= r; ++c) acc += A[TRI(r, c)] * hv[c];
        tv[r] = acc;
    }
    #pragma unroll
    for (int c = 0; c < P_; ++c) {
        float acc = 0.f;
        #pragma unroll
        for (int r = c; r < P_; ++r) acc += A[TRI(r, c)] * tv[r];
        wv[c] = acc;
    }

    float4* rb = (float4*)ws + ((size_t)(q >> 4) * (GSTR / 4)) + (q & 15) * 4;
    #pragma unroll
    for (int m = 0; m < P_; ++m) {
        float v[P_];
        #pragma unroll
        for (int r = 0; r < P_; ++r) v[r] = (r < m) ? 0.f : A[TRI(r, m)];
        if (m == 15) { v[0] = l2; v[1] = s2l; }
        float4* cp = rb + m * 64;
        cp[0] = make_float4(v[ 0], v[ 1], v[ 2], v[ 3]);
        cp[1] = make_float4(v[ 4], v[ 5], v[ 6], v[ 7]);
        cp[2] = make_float4(v[ 8], v[ 9], v[10], v[11]);
        cp[3] = make_float4(v[12], v[13], v[14], v[15]);
    }
    {
        float4* zp = rb + 16 * 64;
        zp[0] = make_float4(zv[ 0], zv[ 1], zv[ 2], zv[ 3]);
        zp[1] = make_float4(zv[ 4], zv[ 5], zv[ 6], zv[ 7]);
        zp[2] = make_float4(zv[ 8], zv[ 9], zv[10], zv[11]);
        zp[3] = make_float4(zv[12], zv[13], zv[14], zv[15]);
        float4* wp = rb + 17 * 64;
        wp[0] = make_float4(wv[ 0], wv[ 1], wv[ 2], wv[ 3]);
        wp[1] = make_float4(wv[ 4], wv[ 5], wv[ 6], wv[ 7]);
        wp[2] = make_float4(wv[ 8], wv[ 9], wv[10], wv[11]);
        wp[3] = make_float4(wv[12], wv[13], wv[14], wv[15]);
    }
}

// ============================ Kernel 2: sites ==============================
// Wave = one o. R9 change: record loads are VECTOR global_load_dwordx4
// (uniform address -> one cacheline per inst), NOT s_load. R8 lesson: the
// 1152B record can't fit in SGPRs, so the scalar path serialized on lgkmcnt
// (VALUBusy 28%, 110us stall). ~49 independent vmem loads per wave-i give
// deep vmcnt pipelining; latency hidden by MLP + occupancy. No readfirstlane.
__global__ __launch_bounds__(256, 2) void gp_sites(
    const float* __restrict__ x_mean, const float* __restrict__ x_var,
    const float* __restrict__ ws, float* __restrict__ out)
{
    __shared__ float xm_s[N_][IT + 1];
    __shared__ float xv_s[N_][IT + 1];

    const int t = threadIdx.x;
    const int b = blockIdx.x;
    const int ot = b & 63;
    const int ir = b >> 6;
    const int i0 = ir * IT;

    {
        const int n = t >> 1, qq = t & 1;
        const float4 xm4 = *(const float4*)(x_mean + n * I_ + i0 + qq * 4);
        const float4 xv4 = *(const float4*)(x_var  + n * I_ + i0 + qq * 4);
        xm_s[n][qq*4+0] = xm4.x; xm_s[n][qq*4+1] = xm4.y;
        xm_s[n][qq*4+2] = xm4.z; xm_s[n][qq*4+3] = xm4.w;
        xv_s[n][qq*4+0] = xv4.x; xv_s[n][qq*4+1] = xv4.y;
        xv_s[n][qq*4+2] = xv4.z; xv_s[n][qq*4+3] = xv4.w;
    }
    __syncthreads();

    f2 am2 = {0.f, 0.f};
    f2 av2 = {IT * 0.1f, IT * 0.1f};   // GLOBAL_JITTER per i

    const int ol = t >> 6;   // o_local (0..3), one per wave (kept divergent!)
    const int ln = t & 63;   // sites n = ln and ln+64
    const int o  = ot * OT + ol;

    for (int ii = 0; ii < IT; ++ii) {
        const int i = i0 + ii;
        const int q = i * O_ + o;                        // wave-uniform value
        const float* rec = ws + ((size_t)(q >> 4) * GSTR + (size_t)(q & 15) * 16);

        // z, w, scalars — vector loads (uniform addr, 1 line each)
        float zr[P_], wr[P_];
        {
            const float4* zp4 = (const float4*)(rec + 16 * 256);
            const float4* wp4 = (const float4*)(rec + 17 * 256);
            #pragma unroll
            for (int c = 0; c < 4; ++c) {
                const float4 z4 = zp4[c], w4 = wp4[c];
                zr[4*c+0] = z4.x; zr[4*c+1] = z4.y; zr[4*c+2] = z4.z; zr[4*c+3] = z4.w;
                wr[4*c+0] = w4.x; wr[4*c+1] = w4.y; wr[4*c+2] = w4.z; wr[4*c+3] = w4.w;
            }
        }
        const float2 sc = *(const float2*)(rec + 15 * 256);
        const float l2  = sc.x;
        const float s2l = sc.y;
        const float t4v = SQRT_2PI * s2l;

        f2 xm2, xv2;
        xm2.x = xm_s[ln][ii];       xm2.y = xm_s[ln + 64][ii];
        xv2.x = xv_s[ln][ii];       xv2.y = xv_s[ln + 64][ii];
        f2 v2 = xv2 + l2;
        f2 cc2, nh2;
        cc2.x = rsqrtf(v2.x) * INV_SQRT_2PI;
        cc2.y = rsqrtf(v2.y) * INV_SQRT_2PI;
        nh2.x = -0.5f / v2.x;
        nh2.y = -0.5f / v2.y;
        f2 dm2 = {0.f, 0.f};

        f2 u2[P_];
        #pragma unroll
        for (int m = 0; m < P_; ++m) {
            f2 d2 = xm2 - zr[m];
            f2 tt = d2 * d2 * nh2;
            f2 em2;
            em2.x = __expf(tt.x);
            em2.y = __expf(tt.y);
            dm2 += em2 * wr[m];

            const float4* col = (const float4*)(rec + m * 256);
            const int c0 = m >> 2;      // static after unroll
            #pragma unroll
            for (int c = 0; c < 4; ++c) {
                if (c < c0) continue;   // rows above diag chunk: zeros, skip
                const float4 L4 = col[c];
                if (m == 0) {
                    u2[4*c+0] = L4.x * em2;
                    u2[4*c+1] = L4.y * em2;
                    u2[4*c+2] = L4.z * em2;
                    u2[4*c+3] = L4.w * em2;
                } else {
                    u2[4*c+0] += L4.x * em2;
                    u2[4*c+1] += L4.y * em2;
                    u2[4*c+2] += L4.z * em2;
                    u2[4*c+3] += L4.w * em2;
                }
            }
        }

        f2 su2 = {0.f, 0.f};
        #pragma unroll
        for (int r = 0; r < P_; ++r) su2 += u2[r] * u2[r];

        am2 += cc2 * dm2;
        f2 t32;
        t32.x = s2l * rsqrtf(l2 + 2.f * xv2.x);
        t32.y = s2l * rsqrtf(l2 + 2.f * xv2.y);
        av2 += t32 - t4v * (cc2 * cc2) * su2;
    }

    atomicAdd(out + ln * O_ + o,                  am2.x);
    atomicAdd(out + (ln + 64) * O_ + o,           am2.y);
    atomicAdd(out + N_ * O_ + ln * O_ + o,        av2.x);
    atomicAdd(out + N_ * O_ + (ln + 64) * O_ + o, av2.y);
}

// ===================== Fallback: R5 monolithic kernel ======================
#define LSTR 20
__global__ __launch_bounds__(256, 2) void gp_fused(
    const float* __restrict__ x_mean, const float* __restrict__ x_var,
    const float* __restrict__ z_param, const float* __restrict__ h,
    const float* __restrict__ l_param, const float* __restrict__ s_param,
    const float* __restrict__ jitter_param, float* __restrict__ out)
{
    __shared__ float xm_s[N_][IT + 1];
    __shared__ float xv_s[N_][IT + 1];
    __shared__ __align__(16) float LinvT[ICH][OT][P_][LSTR];
    __shared__ __align__(16) float zS[ICH][OT][P_];
    __shared__ __align__(16) float wS[ICH][OT][P_];
    __shared__ float scS[ICH][OT][2];

    const int t = threadIdx.x;
    const int b = blockIdx.x;
    const int ot = b & 63;
    const int ir = b >> 6;
    const int o_base = ot * OT;
    const int i0 = ir * IT;

    {
        const int n = t >> 1, q = t & 1;
        const float4 xm4 = *(const float4*)(x_mean + n * I_ + i0 + q * 4);
        const float4 xv4 = *(const float4*)(x_var  + n * I_ + i0 + q * 4);
        xm_s[n][q*4+0] = xm4.x; xm_s[n][q*4+1] = xm4.y;
        xm_s[n][q*4+2] = xm4.z; xm_s[n][q*4+3] = xm4.w;
        xv_s[n][q*4+0] = xv4.x; xv_s[n][q*4+1] = xv4.y;
        xv_s[n][q*4+2] = xv4.z; xv_s[n][q*4+3] = xv4.w;
    }
    __syncthreads();

    f2 am2 = {0.f, 0.f};
    f2 av2 = {IT * 0.1f, IT * 0.1f};

    const int ol = t >> 6;
    const int ln = t & 63;
    const int g2 = t >> 4;
    const int il = g2 >> 2;
    const int g  = g2 & 3;
    const int p  = t & 15;

    for (int ii4 = 0; ii4 < IT / ICH; ++ii4) {
        {
            const int i  = i0 + ii4 * ICH + il;
            const int o  = o_base + g;
            const int io = i * O_ + o;
            const float l   = expf(l_param[io]) + 0.2f;
            const float s   = expf(s_param[io]) + 0.1f;
            const float jit = expf(jitter_param[io]) + 0.01f;
            const float l2 = l * l;
            const float inv2l2 = 0.5f / l2;
            const float cQ = INV_SQRT_2PI / l;
            const float noise = jit * jit / (s * s * l * SQRT_2PI);
            const float zp = tanhf(z_param[io * P_ + p]);

            float a[P_];
            #pragma unroll
            for (int c = 0; c < P_; ++c) {
                const float zc = __shfl(zp, c, P_);
                const float d = zp - zc;
                a[c] = cQ * __expf(-d * d * inv2l2) + ((c == p) ? noise : 0.0f);
            }
            #pragma unroll
            for (int k = 0; k < P_; ++k) {
                const float akk = __shfl(a[k], k, P_);
                const float lkk = sqrtf(akk);
                const float inv_lkk = 1.0f / lkk;
                if (p == k)      a[k] = lkk;
                else if (p > k)  a[k] *= inv_lkk;
                const float lrk = a[k];
                #pragma unroll
                for (int c = k + 1; c < P_; ++c) {
                    const float lck = __shfl(a[k], c, P_);
                    if (p >= c) a[c] -= lrk * lck;
                }
            }
            float x[P_];
            #pragma unroll
            for (int r = 0; r < P_; ++r) {
                const float lrr = __shfl(a[r], r, P_);
                float acc = (r == p) ? 1.0f : 0.0f;
                #pragma unroll
                for (int m = 0; m < r; ++m) {
                    const float lrm = __shfl(a[m], r, P_);
                    acc -= lrm * x[m];
                }
                x[r] = acc / lrr;
            }
            const float hc = h[io * P_ + p];
            float y[P_];
            #pragma unroll
            for (int r = 0; r < P_; ++r) y[r] = x[r] * hc;
            #pragma unroll
            for (int off = 8; off >= 1; off >>= 1) {
                #pragma unroll
                for (int r = 0; r < P_; ++r) y[r] += __shfl_xor(y[r], off, P_);
            }
            float wc = 0.f;
            #pragma unroll
            for (int r = 0; r < P_; ++r) wc += x[r] * y[r];

            float4* dst = (float4*)&LinvT[il][g][p][0];
            dst[0] = make_float4(x[ 0], x[ 1], x[ 2], x[ 3]);
            dst[1] = make_float4(x[ 4], x[ 5], x[ 6], x[ 7]);
            dst[2] = make_float4(x[ 8], x[ 9], x[10], x[11]);
            dst[3] = make_float4(x[12], x[13], x[14], x[15]);
            zS[il][g][p] = zp;
            wS[il][g][p] = wc;
            if (p == 0) { scS[il][g][0] = l2; scS[il][g][1] = s * s * l; }
        }
        __syncthreads();

        #pragma unroll
        for (int il2 = 0; il2 < ICH; ++il2) {
            const int iiA = ii4 * ICH + il2;
            const float l2  = scS[il2][ol][0];
            const float s2l = scS[il2][ol][1];
            const float t4v = SQRT_2PI * s2l;
            float zr[P_], wr[P_];
            {
                const float4* zp4 = (const float4*)&zS[il2][ol][0];
                const float4* wp4 = (const float4*)&wS[il2][ol][0];
                #pragma unroll
                for (int c = 0; c < 4; ++c) {
                    const float4 z4 = zp4[c], w4 = wp4[c];
                    zr[4*c+0] = z4.x; zr[4*c+1] = z4.y; zr[4*c+2] = z4.z; zr[4*c+3] = z4.w;
                    wr[4*c+0] = w4.x; wr[4*c+1] = w4.y; wr[4*c+2] = w4.z; wr[4*c+3] = w4.w;
                }
            }
            f2 xm2, xv2;
            xm2.x = xm_s[ln][iiA];       xm2.y = xm_s[ln + 64][iiA];
            xv2.x = xv_s[ln][iiA];       xv2.y = xv_s[ln + 64][iiA];
            f2 v2 = xv2 + l2;
            f2 cc2, nh2;
            cc2.x = rsqrtf(v2.x) * INV_SQRT_2PI;
            cc2.y = rsqrtf(v2.y) * INV_SQRT_2PI;
            nh2.x = -0.5f / v2.x;
            nh2.y = -0.5f / v2.y;
            f2 dm2 = {0.f, 0.f};
            f2 u2[P_];
            #pragma unroll
            for (int m = 0; m < P_; ++m) {
                f2 d2 = xm2 - zr[m];
                f2 tt = d2 * d2 * nh2;
                f2 em2;
                em2.x = __expf(tt.x);
                em2.y = __expf(tt.y);
                dm2 += em2 * wr[m];
                const int c0 = m >> 2;
                #pragma unroll
                for (int c = 0; c < 4; ++c) {
                    if (c < c0) continue;
                    const float4 L4 = *(const float4*)&LinvT[il2][ol][m][4*c];
                    if (m == 0) {
                        u2[4*c+0] = L4.x * em2;
                        u2[4*c+1] = L4.y * em2;
                        u2[4*c+2] = L4.z * em2;
                        u2[4*c+3] = L4.w * em2;
                    } else {
                        u2[4*c+0] += L4.x * em2;
                        u2[4*c+1] += L4.y * em2;
                        u2[4*c+2] += L4.z * em2;
                        u2[4*c+3] += L4.w * em2;
                    }
                }
            }
            f2 su2 = {0.f, 0.f};
            #pragma unroll
            for (int r = 0; r < P_; ++r) su2 += u2[r] * u2[r];
            am2 += cc2 * dm2;
            f2 t32;
            t32.x = s2l * rsqrtf(l2 + 2.f * xv2.x);
            t32.y = s2l * rsqrtf(l2 + 2.f * xv2.y);
            av2 += t32 - t4v * (cc2 * cc2) * su2;
        }
        __syncthreads();
    }

    const int o = o_base + ol;
    atomicAdd(out + ln * O_ + o,                  am2.x);
    atomicAdd(out + (ln + 64) * O_ + o,           am2.y);
    atomicAdd(out + N_ * O_ + ln * O_ + o,        av2.x);
    atomicAdd(out + N_ * O_ + (ln + 64) * O_ + o, av2.y);
}

extern "C" void kernel_launch(void* const* d_in, const int* in_sizes, int n_in,
                              void* d_out, int out_size, void* d_ws, size_t ws_size,
                              hipStream_t stream) {
    const float* x_mean = (const float*)d_in[0];
    const float* x_var  = (const float*)d_in[1];
    const float* z_param = (const float*)d_in[2];
    const float* h       = (const float*)d_in[3];
    const float* l_param = (const float*)d_in[4];
    const float* s_param = (const float*)d_in[5];
    const float* jitter_param = (const float*)d_in[6];
    float* out = (float*)d_out;

    hipMemsetAsync(d_out, 0, (size_t)out_size * sizeof(float), stream);
    if (ws_size >= NEED_BYTES) {
        gp_pairs<<<dim3(1024), dim3(64), 0, stream>>>(
            z_param, h, l_param, s_param, jitter_param, (float*)d_ws);
        gp_sites<<<dim3(2048), dim3(256), 0, stream>>>(
            x_mean, x_var, (const float*)d_ws, out);
    } else {
        gp_fused<<<dim3(2048), dim3(256), 0, stream>>>(
            x_mean, x_var, z_param, h, l_param, s_param, jitter_param, out);
    }
}

// Round 10
// 273.463 us; speedup vs baseline: 1.0813x; 1.0813x over previous
//
#include <hip/hip_runtime.h>
#include <math.h>

#define N_ 128
#define I_ 256
#define O_ 256
#define P_ 16
#define OT 4      // o's per block (site kernel)
#define IT 8      // i's per block (site kernel)
#define ICH 4     // fallback kernel chunking
#define SQRT_2PI 2.5066282746310002f
#define INV_SQRT_2PI 0.3989422804014327f

// ---- Packed record layout (R10) ----
// Per pair: 49 float4s in EXACT consumption order, interleaved per 16-pair
// group in 64B units so pairs' stores coalesce:
//   unit j (64B = 4 float4) of pair q at float offset
//     (q>>4)*3328 + j*256 + (q&15)*16
//   units 0..9  : 40 float4s of M = L^-1, packed (m asc, c = (m>>2)..3);
//                 chunk c covers rows 4c..4c+3 of column m (diag inverted,
//                 zeros above diag omitted entirely)
//   unit 10 : z (16 floats), unit 11 : w (16), unit 12 : l2, s2l, pad
#define GF 3328                    // floats per 16-pair group (13 units)
#define NEED_BYTES ((size_t)4096 * GF * 4)   // 54.5 MB

#define TRI(r, c) ((r) * ((r) + 1) / 2 + (c))

typedef float f2 __attribute__((ext_vector_type(2)));

__device__ __forceinline__ float fast_tanh(float x) {
    const float e2 = __expf(2.0f * x);
    return 1.0f - 2.0f / (e2 + 1.0f);
}

// ============================ Kernel 1: pairs ==============================
// ONE THREAD PER PAIR (65536 threads). Whole triangle in regs, sequential
// Cholesky + in-place inversion + w. Zero cross-lane ops.
__global__ __launch_bounds__(64, 1) void gp_pairs(
    const float* __restrict__ z_param, const float* __restrict__ h,
    const float* __restrict__ l_param, const float* __restrict__ s_param,
    const float* __restrict__ jitter_param, float* __restrict__ ws)
{
    const int q = blockIdx.x * 64 + threadIdx.x;   // pair index = i*256 + o
    const int io = q;

    const float l   = __expf(l_param[io]) + 0.2f;
    const float s   = __expf(s_param[io]) + 0.1f;
    const float jit = __expf(jitter_param[io]) + 0.01f;
    const float l2 = l * l;
    const float ninv2l2 = -0.5f / l2;
    const float cQ = INV_SQRT_2PI / l;
    const float noise = jit * jit / (s * s * l * SQRT_2PI);
    const float s2l = s * s * l;

    float zv[P_], hv[P_];
    {
        const float4* zp = (const float4*)(z_param + (size_t)io * P_);
        const float4* hp = (const float4*)(h + (size_t)io * P_);
        #pragma unroll
        for (int c = 0; c < 4; ++c) {
            const float4 z4 = zp[c], h4 = hp[c];
            zv[4*c+0] = z4.x; zv[4*c+1] = z4.y; zv[4*c+2] = z4.z; zv[4*c+3] = z4.w;
            hv[4*c+0] = h4.x; hv[4*c+1] = h4.y; hv[4*c+2] = h4.z; hv[4*c+3] = h4.w;
        }
    }
    #pragma unroll
    for (int p = 0; p < P_; ++p) zv[p] = fast_tanh(zv[p]);

    float A[136];
    #pragma unroll
    for (int r = 0; r < P_; ++r) {
        #pragma unroll
        for (int c = 0; c <= r; ++c) {
            const float d = zv[r] - zv[c];
            A[TRI(r, c)] = cQ * __expf(d * d * ninv2l2) + ((r == c) ? noise : 0.f);
        }
    }

    float dinv[P_];
    #pragma unroll
    for (int k = 0; k < P_; ++k) {
        const float Lkk = sqrtf(A[TRI(k, k)]);
        const float ik = 1.0f / Lkk;
        dinv[k] = ik;
        A[TRI(k, k)] = Lkk;
        #pragma unroll
        for (int r = k + 1; r < P_; ++r) A[TRI(r, k)] *= ik;
        #pragma unroll
        for (int c = k + 1; c < P_; ++c) {
            const float Lck = A[TRI(c, k)];
            #pragma unroll
            for (int r = c; r < P_; ++r) A[TRI(r, c)] -= A[TRI(r, k)] * Lck;
        }
    }

    #pragma unroll
    for (int j = 0; j < P_; ++j) {
        #pragma unroll
        for (int r = j + 1; r < P_; ++r) {
            float acc = A[TRI(r, j)] * dinv[j];
            #pragma unroll
            for (int k = j + 1; k < r; ++k) acc += A[TRI(r, k)] * A[TRI(k, j)];
            A[TRI(r, j)] = -dinv[r] * acc;
        }
        A[TRI(j, j)] = dinv[j];
    }

    float tv[P_], wv[P_];
    #pragma unroll
    for (int r = 0; r < P_; ++r) {
        float acc = 0.f;
        #pragma unroll
        for (int c = 0; c <= r; ++c) acc += A[TRI(r, c)] * hv[c];
        tv[r] = acc;
    }
    #pragma unroll
    for (int c = 0; c < P_; ++c) {
        float acc = 0.f;
        #pragma unroll
        for (int r = c; r < P_; ++r) acc += A[TRI(r, c)] * tv[r];
        wv[c] = acc;
    }

    // ---- store packed record ----
    float4* rb = (float4*)ws + (size_t)(q >> 4) * (GF / 4) + (size_t)(q & 15) * 4;
    {
        float4 buf[4];
        int k = 0;
        #pragma unroll
        for (int m = 0; m < P_; ++m) {
            #pragma unroll
            for (int c = (m >> 2); c < 4; ++c) {
                float vv[4];
                #pragma unroll
                for (int rr = 0; rr < 4; ++rr) {
                    const int r = 4 * c + rr;
                    vv[rr] = (r < m) ? 0.f : A[TRI(r, m)];
                }
                buf[k & 3] = make_float4(vv[0], vv[1], vv[2], vv[3]);
                if ((k & 3) == 3) {
                    float4* up = rb + (size_t)(k >> 2) * 64;
                    up[0] = buf[0]; up[1] = buf[1]; up[2] = buf[2]; up[3] = buf[3];
                }
                ++k;
            }
        }
    }
    {
        float4* zp = rb + 10 * 64;
        zp[0] = make_float4(zv[ 0], zv[ 1], zv[ 2], zv[ 3]);
        zp[1] = make_float4(zv[ 4], zv[ 5], zv[ 6], zv[ 7]);
        zp[2] = make_float4(zv[ 8], zv[ 9], zv[10], zv[11]);
        zp[3] = make_float4(zv[12], zv[13], zv[14], zv[15]);
        float4* wp = rb + 11 * 64;
        wp[0] = make_float4(wv[ 0], wv[ 1], wv[ 2], wv[ 3]);
        wp[1] = make_float4(wv[ 4], wv[ 5], wv[ 6], wv[ 7]);
        wp[2] = make_float4(wv[ 8], wv[ 9], wv[10], wv[11]);
        wp[3] = make_float4(wv[12], wv[13], wv[14], wv[15]);
        float4* sp = rb + 12 * 64;
        sp[0] = make_float4(l2, s2l, 0.f, 0.f);
    }
}

// ============================ Kernel 2: sites ==============================
// Wave = one o. VMEM record path with EXPLICIT depth-4 column pipeline:
// prime sc/z/w/cols0-3 (25 loads in flight), then per m consume col m from
// the ring cb[m&3] and issue col m+4's loads. R9 lesson: without this, each
// column load is a serial ~600-900cyc HBM/L3 miss (75MB stream > 32MB L2).
__global__ __launch_bounds__(256, 2) void gp_sites(
    const float* __restrict__ x_mean, const float* __restrict__ x_var,
    const float* __restrict__ ws, float* __restrict__ out)
{
    __shared__ float xm_s[N_][IT + 1];
    __shared__ float xv_s[N_][IT + 1];

    const int t = threadIdx.x;
    const int b = blockIdx.x;
    const int ot = b & 63;
    const int ir = b >> 6;
    const int i0 = ir * IT;

    {
        const int n = t >> 1, qq = t & 1;
        const float4 xm4 = *(const float4*)(x_mean + n * I_ + i0 + qq * 4);
        const float4 xv4 = *(const float4*)(x_var  + n * I_ + i0 + qq * 4);
        xm_s[n][qq*4+0] = xm4.x; xm_s[n][qq*4+1] = xm4.y;
        xm_s[n][qq*4+2] = xm4.z; xm_s[n][qq*4+3] = xm4.w;
        xv_s[n][qq*4+0] = xv4.x; xv_s[n][qq*4+1] = xv4.y;
        xv_s[n][qq*4+2] = xv4.z; xv_s[n][qq*4+3] = xv4.w;
    }
    __syncthreads();

    f2 am2 = {0.f, 0.f};
    f2 av2 = {IT * 0.1f, IT * 0.1f};   // GLOBAL_JITTER per i

    const int ol = t >> 6;   // o_local (0..3), one per wave
    const int ln = t & 63;   // sites n = ln and ln+64
    const int o  = ot * OT + ol;

    for (int ii = 0; ii < IT; ++ii) {
        const int i = i0 + ii;
        const int q = i * O_ + o;                        // wave-uniform value
        const float* rec = ws + (size_t)(q >> 4) * GF + (size_t)(q & 15) * 16;

        // ---- prime the pipeline: sc, z, w, cols 0..3 (25 loads) ----
        const float2 sc = *(const float2*)(rec + 12 * 256);
        float4 z4[4], w4[4];
        #pragma unroll
        for (int c = 0; c < 4; ++c) {
            z4[c] = *(const float4*)(rec + 10 * 256 + c * 4);
            w4[c] = *(const float4*)(rec + 11 * 256 + c * 4);
        }
        float4 cb[4][4];
        #pragma unroll
        for (int s = 0; s < 4; ++s) {
            #pragma unroll
            for (int c = 0; c < 4; ++c)
                cb[s][c] = *(const float4*)(rec + s * 256 + c * 4);  // f4 k=4s+c
        }

        float zr[P_], wr[P_];
        #pragma unroll
        for (int c = 0; c < 4; ++c) {
            zr[4*c+0] = z4[c].x; zr[4*c+1] = z4[c].y; zr[4*c+2] = z4[c].z; zr[4*c+3] = z4[c].w;
            wr[4*c+0] = w4[c].x; wr[4*c+1] = w4[c].y; wr[4*c+2] = w4[c].z; wr[4*c+3] = w4[c].w;
        }

        const float l2  = sc.x;
        const float s2l = sc.y;
        const float t4v = SQRT_2PI * s2l;

        f2 xm2, xv2;
        xm2.x = xm_s[ln][ii];       xm2.y = xm_s[ln + 64][ii];
        xv2.x = xv_s[ln][ii];       xv2.y = xv_s[ln + 64][ii];
        f2 v2 = xv2 + l2;
        f2 cc2, nh2;
        cc2.x = rsqrtf(v2.x) * INV_SQRT_2PI;
        cc2.y = rsqrtf(v2.y) * INV_SQRT_2PI;
        nh2.x = -0.5f / v2.x;
        nh2.y = -0.5f / v2.y;
        f2 dm2 = {0.f, 0.f};

        f2 u2[P_];
        int lk = 16;   // next packed f4 to load (static after unroll)
        #pragma unroll
        for (int m = 0; m < P_; ++m) {
            f2 d2 = xm2 - zr[m];
            f2 tt = d2 * d2 * nh2;
            f2 em2;
            em2.x = __expf(tt.x);
            em2.y = __expf(tt.y);
            dm2 += em2 * wr[m];

            const int c0 = m >> 2;
            #pragma unroll
            for (int c = c0; c < 4; ++c) {
                const float4 L4 = cb[m & 3][c];
                if (m == 0) {
                    u2[4*c+0] = L4.x * em2;
                    u2[4*c+1] = L4.y * em2;
                    u2[4*c+2] = L4.z * em2;
                    u2[4*c+3] = L4.w * em2;
                } else {
                    u2[4*c+0] += L4.x * em2;
                    u2[4*c+1] += L4.y * em2;
                    u2[4*c+2] += L4.z * em2;
                    u2[4*c+3] += L4.w * em2;
                }
            }
            // prefetch column m+4 into the slot just freed
            if (m < 12) {
                const int mc0 = (m + 4) >> 2;
                #pragma unroll
                for (int c = mc0; c < 4; ++c) {
                    cb[m & 3][c] = *(const float4*)(rec + (lk >> 2) * 256 + (lk & 3) * 4);
                    ++lk;
                }
            }
        }

        f2 su2 = {0.f, 0.f};
        #pragma unroll
        for (int r = 0; r < P_; ++r) su2 += u2[r] * u2[r];

        am2 += cc2 * dm2;
        f2 t32;
        t32.x = s2l * rsqrtf(l2 + 2.f * xv2.x);
        t32.y = s2l * rsqrtf(l2 + 2.f * xv2.y);
        av2 += t32 - t4v * (cc2 * cc2) * su2;
    }

    atomicAdd(out + ln * O_ + o,                  am2.x);
    atomicAdd(out + (ln + 64) * O_ + o,           am2.y);
    atomicAdd(out + N_ * O_ + ln * O_ + o,        av2.x);
    atomicAdd(out + N_ * O_ + (ln + 64) * O_ + o, av2.y);
}

// ===================== Fallback: R5 monolithic kernel ======================
#define LSTR 20
__global__ __launch_bounds__(256, 2) void gp_fused(
    const float* __restrict__ x_mean, const float* __restrict__ x_var,
    const float* __restrict__ z_param, const float* __restrict__ h,
    const float* __restrict__ l_param, const float* __restrict__ s_param,
    const float* __restrict__ jitter_param, float* __restrict__ out)
{
    __shared__ float xm_s[N_][IT + 1];
    __shared__ float xv_s[N_][IT + 1];
    __shared__ __align__(16) float LinvT[ICH][OT][P_][LSTR];
    __shared__ __align__(16) float zS[ICH][OT][P_];
    __shared__ __align__(16) float wS[ICH][OT][P_];
    __shared__ float scS[ICH][OT][2];

    const int t = threadIdx.x;
    const int b = blockIdx.x;
    const int ot = b & 63;
    const int ir = b >> 6;
    const int o_base = ot * OT;
    const int i0 = ir * IT;

    {
        const int n = t >> 1, q = t & 1;
        const float4 xm4 = *(const float4*)(x_mean + n * I_ + i0 + q * 4);
        const float4 xv4 = *(const float4*)(x_var  + n * I_ + i0 + q * 4);
        xm_s[n][q*4+0] = xm4.x; xm_s[n][q*4+1] = xm4.y;
        xm_s[n][q*4+2] = xm4.z; xm_s[n][q*4+3] = xm4.w;
        xv_s[n][q*4+0] = xv4.x; xv_s[n][q*4+1] = xv4.y;
        xv_s[n][q*4+2] = xv4.z; xv_s[n][q*4+3] = xv4.w;
    }
    __syncthreads();

    f2 am2 = {0.f, 0.f};
    f2 av2 = {IT * 0.1f, IT * 0.1f};

    const int ol = t >> 6;
    const int ln = t & 63;
    const int g2 = t >> 4;
    const int il = g2 >> 2;
    const int g  = g2 & 3;
    const int p  = t & 15;

    for (int ii4 = 0; ii4 < IT / ICH; ++ii4) {
        {
            const int i  = i0 + ii4 * ICH + il;
            const int o  = o_base + g;
            const int io = i * O_ + o;
            const float l   = expf(l_param[io]) + 0.2f;
            const float s   = expf(s_param[io]) + 0.1f;
            const float jit = expf(jitter_param[io]) + 0.01f;
            const float l2 = l * l;
            const float inv2l2 = 0.5f / l2;
            const float cQ = INV_SQRT_2PI / l;
            const float noise = jit * jit / (s * s * l * SQRT_2PI);
            const float zp = tanhf(z_param[io * P_ + p]);

            float a[P_];
            #pragma unroll
            for (int c = 0; c < P_; ++c) {
                const float zc = __shfl(zp, c, P_);
                const float d = zp - zc;
                a[c] = cQ * __expf(-d * d * inv2l2) + ((c == p) ? noise : 0.0f);
            }
            #pragma unroll
            for (int k = 0; k < P_; ++k) {
                const float akk = __shfl(a[k], k, P_);
                const float lkk = sqrtf(akk);
                const float inv_lkk = 1.0f / lkk;
                if (p == k)      a[k] = lkk;
                else if (p > k)  a[k] *= inv_lkk;
                const float lrk = a[k];
                #pragma unroll
                for (int c = k + 1; c < P_; ++c) {
                    const float lck = __shfl(a[k], c, P_);
                    if (p >= c) a[c] -= lrk * lck;
                }
            }
            float x[P_];
            #pragma unroll
            for (int r = 0; r < P_; ++r) {
                const float lrr = __shfl(a[r], r, P_);
                float acc = (r == p) ? 1.0f : 0.0f;
                #pragma unroll
                for (int m = 0; m < r; ++m) {
                    const float lrm = __shfl(a[m], r, P_);
                    acc -= lrm * x[m];
                }
                x[r] = acc / lrr;
            }
            const float hc = h[io * P_ + p];
            float y[P_];
            #pragma unroll
            for (int r = 0; r < P_; ++r) y[r] = x[r] * hc;
            #pragma unroll
            for (int off = 8; off >= 1; off >>= 1) {
                #pragma unroll
                for (int r = 0; r < P_; ++r) y[r] += __shfl_xor(y[r], off, P_);
            }
            float wc = 0.f;
            #pragma unroll
            for (int r = 0; r < P_; ++r) wc += x[r] * y[r];

            float4* dst = (float4*)&LinvT[il][g][p][0];
            dst[0] = make_float4(x[ 0], x[ 1], x[ 2], x[ 3]);
            dst[1] = make_float4(x[ 4], x[ 5], x[ 6], x[ 7]);
            dst[2] = make_float4(x[ 8], x[ 9], x[10], x[11]);
            dst[3] = make_float4(x[12], x[13], x[14], x[15]);
            zS[il][g][p] = zp;
            wS[il][g][p] = wc;
            if (p == 0) { scS[il][g][0] = l2; scS[il][g][1] = s * s * l; }
        }
        __syncthreads();

        #pragma unroll
        for (int il2 = 0; il2 < ICH; ++il2) {
            const int iiA = ii4 * ICH + il2;
            const float l2  = scS[il2][ol][0];
            const float s2l = scS[il2][ol][1];
            const float t4v = SQRT_2PI * s2l;
            float zr[P_], wr[P_];
            {
                const float4* zp4 = (const float4*)&zS[il2][ol][0];
                const float4* wp4 = (const float4*)&wS[il2][ol][0];
                #pragma unroll
                for (int c = 0; c < 4; ++c) {
                    const float4 z4 = zp4[c], w4 = wp4[c];
                    zr[4*c+0] = z4.x; zr[4*c+1] = z4.y; zr[4*c+2] = z4.z; zr[4*c+3] = z4.w;
                    wr[4*c+0] = w4.x; wr[4*c+1] = w4.y; wr[4*c+2] = w4.z; wr[4*c+3] = w4.w;
                }
            }
            f2 xm2, xv2;
            xm2.x = xm_s[ln][iiA];       xm2.y = xm_s[ln + 64][iiA];
            xv2.x = xv_s[ln][iiA];       xv2.y = xv_s[ln + 64][iiA];
            f2 v2 = xv2 + l2;
            f2 cc2, nh2;
            cc2.x = rsqrtf(v2.x) * INV_SQRT_2PI;
            cc2.y = rsqrtf(v2.y) * INV_SQRT_2PI;
            nh2.x = -0.5f / v2.x;
            nh2.y = -0.5f / v2.y;
            f2 dm2 = {0.f, 0.f};
            f2 u2[P_];
            #pragma unroll
            for (int m = 0; m < P_; ++m) {
                f2 d2 = xm2 - zr[m];
                f2 tt = d2 * d2 * nh2;
                f2 em2;
                em2.x = __expf(tt.x);
                em2.y = __expf(tt.y);
                dm2 += em2 * wr[m];
                const int c0 = m >> 2;
                #pragma unroll
                for (int c = 0; c < 4; ++c) {
                    if (c < c0) continue;
                    const float4 L4 = *(const float4*)&LinvT[il2][ol][m][4*c];
                    if (m == 0) {
                        u2[4*c+0] = L4.x * em2;
                        u2[4*c+1] = L4.y * em2;
                        u2[4*c+2] = L4.z * em2;
                        u2[4*c+3] = L4.w * em2;
                    } else {
                        u2[4*c+0] += L4.x * em2;
                        u2[4*c+1] += L4.y * em2;
                        u2[4*c+2] += L4.z * em2;
                        u2[4*c+3] += L4.w * em2;
                    }
                }
            }
            f2 su2 = {0.f, 0.f};
            #pragma unroll
            for (int r = 0; r < P_; ++r) su2 += u2[r] * u2[r];
            am2 += cc2 * dm2;
            f2 t32;
            t32.x = s2l * rsqrtf(l2 + 2.f * xv2.x);
            t32.y = s2l * rsqrtf(l2 + 2.f * xv2.y);
            av2 += t32 - t4v * (cc2 * cc2) * su2;
        }
        __syncthreads();
    }

    const int o = o_base + ol;
    atomicAdd(out + ln * O_ + o,                  am2.x);
    atomicAdd(out + (ln + 64) * O_ + o,           am2.y);
    atomicAdd(out + N_ * O_ + ln * O_ + o,        av2.x);
    atomicAdd(out + N_ * O_ + (ln + 64) * O_ + o, av2.y);
}

extern "C" void kernel_launch(void* const* d_in, const int* in_sizes, int n_in,
                              void* d_out, int out_size, void* d_ws, size_t ws_size,
                              hipStream_t stream) {
    const float* x_mean = (const float*)d_in[0];
    const float* x_var  = (const float*)d_in[1];
    const float* z_param = (const float*)d_in[2];
    const float* h       = (const float*)d_in[3];
    const float* l_param = (const float*)d_in[4];
    const float* s_param = (const float*)d_in[5];
    const float* jitter_param = (const float*)d_in[6];
    float* out = (float*)d_out;

    hipMemsetAsync(d_out, 0, (size_t)out_size * sizeof(float), stream);
    if (ws_size >= NEED_BYTES) {
        gp_pairs<<<dim3(1024), dim3(64), 0, stream>>>(
            z_param, h, l_param, s_param, jitter_param, (float*)d_ws);
        gp_sites<<<dim3(2048), dim3(256), 0, stream>>>(
            x_mean, x_var, (const float*)d_ws, out);
    } else {
        gp_fused<<<dim3(2048), dim3(256), 0, stream>>>(
            x_mean, x_var, z_param, h, l_param, s_param, jitter_param, out);
    }
}

// Round 11
// 218.905 us; speedup vs baseline: 1.3508x; 1.2492x over previous
//
#include <hip/hip_runtime.h>
#include <math.h>

#define N_ 128
#define I_ 256
#define O_ 256
#define P_ 16
#define OT 4      // o's per block (site kernel)
#define IT 8      // i's per block (site kernel)
#define ICH 4     // fallback kernel chunking
#define SQRT_2PI 2.5066282746310002f
#define INV_SQRT_2PI 0.3989422804014327f

// ---- Packed record layout (R10/R11) ----
// Per pair: 13 units of 64B (832B), interleaved per 16-pair group:
//   unit j of pair q at float offset (q>>4)*3328 + j*256 + (q&15)*16
//   units 0..9 : 40 float4s of M = L^-1 in consumption order (m asc,
//                c = (m>>2)..3; diag inverted; zeros above diag omitted)
//   unit 10 : z, unit 11 : w, unit 12 : l2, s2l, pad
#define GF 3328                    // floats per 16-pair group
#define NEED_BYTES ((size_t)4096 * GF * 4)   // 54.5 MB

#define TRI(r, c) ((r) * ((r) + 1) / 2 + (c))

typedef float f2 __attribute__((ext_vector_type(2)));

__device__ __forceinline__ float fast_tanh(float x) {
    const float e2 = __expf(2.0f * x);
    return 1.0f - 2.0f / (e2 + 1.0f);
}

// ============================ Kernel 1: pairs ==============================
// ONE THREAD PER PAIR (65536 threads). Whole triangle in regs, sequential
// Cholesky + in-place inversion + w. Zero cross-lane ops.
__global__ __launch_bounds__(64, 1) void gp_pairs(
    const float* __restrict__ z_param, const float* __restrict__ h,
    const float* __restrict__ l_param, const float* __restrict__ s_param,
    const float* __restrict__ jitter_param, float* __restrict__ ws)
{
    const int q = blockIdx.x * 64 + threadIdx.x;   // pair index = i*256 + o
    const int io = q;

    const float l   = __expf(l_param[io]) + 0.2f;
    const float s   = __expf(s_param[io]) + 0.1f;
    const float jit = __expf(jitter_param[io]) + 0.01f;
    const float l2 = l * l;
    const float ninv2l2 = -0.5f / l2;
    const float cQ = INV_SQRT_2PI / l;
    const float noise = jit * jit / (s * s * l * SQRT_2PI);
    const float s2l = s * s * l;

    float zv[P_], hv[P_];
    {
        const float4* zp = (const float4*)(z_param + (size_t)io * P_);
        const float4* hp = (const float4*)(h + (size_t)io * P_);
        #pragma unroll
        for (int c = 0; c < 4; ++c) {
            const float4 z4 = zp[c], h4 = hp[c];
            zv[4*c+0] = z4.x; zv[4*c+1] = z4.y; zv[4*c+2] = z4.z; zv[4*c+3] = z4.w;
            hv[4*c+0] = h4.x; hv[4*c+1] = h4.y; hv[4*c+2] = h4.z; hv[4*c+3] = h4.w;
        }
    }
    #pragma unroll
    for (int p = 0; p < P_; ++p) zv[p] = fast_tanh(zv[p]);

    float A[136];
    #pragma unroll
    for (int r = 0; r < P_; ++r) {
        #pragma unroll
        for (int c = 0; c <= r; ++c) {
            const float d = zv[r] - zv[c];
            A[TRI(r, c)] = cQ * __expf(d * d * ninv2l2) + ((r == c) ? noise : 0.f);
        }
    }

    float dinv[P_];
    #pragma unroll
    for (int k = 0; k < P_; ++k) {
        const float Lkk = sqrtf(A[TRI(k, k)]);
        const float ik = 1.0f / Lkk;
        dinv[k] = ik;
        A[TRI(k, k)] = Lkk;
        #pragma unroll
        for (int r = k + 1; r < P_; ++r) A[TRI(r, k)] *= ik;
        #pragma unroll
        for (int c = k + 1; c < P_; ++c) {
            const float Lck = A[TRI(c, k)];
            #pragma unroll
            for (int r = c; r < P_; ++r) A[TRI(r, c)] -= A[TRI(r, k)] * Lck;
        }
    }

    #pragma unroll
    for (int j = 0; j < P_; ++j) {
        #pragma unroll
        for (int r = j + 1; r < P_; ++r) {
            float acc = A[TRI(r, j)] * dinv[j];
            #pragma unroll
            for (int k = j + 1; k < r; ++k) acc += A[TRI(r, k)] * A[TRI(k, j)];
            A[TRI(r, j)] = -dinv[r] * acc;
        }
        A[TRI(j, j)] = dinv[j];
    }

    float tv[P_], wv[P_];
    #pragma unroll
    for (int r = 0; r < P_; ++r) {
        float acc = 0.f;
        #pragma unroll
        for (int c = 0; c <= r; ++c) acc += A[TRI(r, c)] * hv[c];
        tv[r] = acc;
    }
    #pragma unroll
    for (int c = 0; c < P_; ++c) {
        float acc = 0.f;
        #pragma unroll
        for (int r = c; r < P_; ++r) acc += A[TRI(r, c)] * tv[r];
        wv[c] = acc;
    }

    // ---- store packed record ----
    float4* rb = (float4*)ws + (size_t)(q >> 4) * (GF / 4) + (size_t)(q & 15) * 4;
    {
        float4 buf[4];
        int k = 0;
        #pragma unroll
        for (int m = 0; m < P_; ++m) {
            #pragma unroll
            for (int c = (m >> 2); c < 4; ++c) {
                float vv[4];
                #pragma unroll
                for (int rr = 0; rr < 4; ++rr) {
                    const int r = 4 * c + rr;
                    vv[rr] = (r < m) ? 0.f : A[TRI(r, m)];
                }
                buf[k & 3] = make_float4(vv[0], vv[1], vv[2], vv[3]);
                if ((k & 3) == 3) {
                    float4* up = rb + (size_t)(k >> 2) * 64;
                    up[0] = buf[0]; up[1] = buf[1]; up[2] = buf[2]; up[3] = buf[3];
                }
                ++k;
            }
        }
    }
    {
        float4* zp = rb + 10 * 64;
        zp[0] = make_float4(zv[ 0], zv[ 1], zv[ 2], zv[ 3]);
        zp[1] = make_float4(zv[ 4], zv[ 5], zv[ 6], zv[ 7]);
        zp[2] = make_float4(zv[ 8], zv[ 9], zv[10], zv[11]);
        zp[3] = make_float4(zv[12], zv[13], zv[14], zv[15]);
        float4* wp = rb + 11 * 64;
        wp[0] = make_float4(wv[ 0], wv[ 1], wv[ 2], wv[ 3]);
        wp[1] = make_float4(wv[ 4], wv[ 5], wv[ 6], wv[ 7]);
        wp[2] = make_float4(wv[ 8], wv[ 9], wv[10], wv[11]);
        wp[3] = make_float4(wv[12], wv[13], wv[14], wv[15]);
        float4* sp = rb + 12 * 64;
        sp[0] = make_float4(l2, s2l, 0.f, 0.f);
    }
}

// ============================ Kernel 2: sites ==============================
// R11: LDS-staged records (the measured-best R6 structure) + packed 832B
// record + ALL 32 records (8i x 4o) staged once -> a single barrier per
// block. Cooperative coalesced staging converts the per-wave serial miss
// chain (R9/R10: 185us) into parallel loads; consumption is ds_read_b128
// broadcast. Wave = one o, f2 lanes = 2 sites/thread, m-outer parallel u2.
__global__ __launch_bounds__(256, 2) void gp_sites(
    const float* __restrict__ x_mean, const float* __restrict__ x_var,
    const float* __restrict__ ws, float* __restrict__ out)
{
    __shared__ float xm_s[N_][IT + 1];
    __shared__ float xv_s[N_][IT + 1];
    __shared__ __align__(16) float4 pbv[32 * 52];   // 32 records x 208 floats

    const int t = threadIdx.x;
    const int b = blockIdx.x;
    const int ot = b & 63;
    const int ir = b >> 6;
    const int i0 = ir * IT;

    // stage x slice
    {
        const int n = t >> 1, qq = t & 1;
        const float4 xm4 = *(const float4*)(x_mean + n * I_ + i0 + qq * 4);
        const float4 xv4 = *(const float4*)(x_var  + n * I_ + i0 + qq * 4);
        xm_s[n][qq*4+0] = xm4.x; xm_s[n][qq*4+1] = xm4.y;
        xm_s[n][qq*4+2] = xm4.z; xm_s[n][qq*4+3] = xm4.w;
        xv_s[n][qq*4+0] = xv4.x; xv_s[n][qq*4+1] = xv4.y;
        xv_s[n][qq*4+2] = xv4.z; xv_s[n][qq*4+3] = xv4.w;
    }

    // stage all 32 records (8 i x 4 o), coalesced: 1664 float4s
    {
        const int g_hi = ot >> 2;
        const int s0x4 = (ot & 3) * 16;         // s0*4 in float4 units
        const float4* wsv = (const float4*)ws;
        #pragma unroll
        for (int k = 0; k < 7; ++k) {
            const int idx = t + k * 256;
            if (idx < 1664) {
                const int run = idx >> 4;       // 0..103 = i*13 + j
                const int f4i = idx & 15;       // (p16-s0)*4 + c
                const int i = run / 13;
                const int j = run - i * 13;
                const int gi = (i0 + i) * 16 + g_hi;
                const float4 v = wsv[(size_t)gi * 832 + j * 64 + s0x4 + f4i];
                pbv[(i * 4 + (f4i >> 2)) * 52 + j * 4 + (f4i & 3)] = v;
            }
        }
    }
    __syncthreads();

    f2 am2 = {0.f, 0.f};
    f2 av2 = {IT * 0.1f, IT * 0.1f};   // GLOBAL_JITTER per i

    const int ol = t >> 6;   // o_local (0..3), one per wave
    const int ln = t & 63;   // sites n = ln and ln+64
    const int o  = ot * OT + ol;

    for (int ii = 0; ii < IT; ++ii) {
        const float4* rp = &pbv[(ii * 4 + ol) * 52];

        const float4 scv = rp[48];
        const float l2  = scv.x;
        const float s2l = scv.y;
        const float t4v = SQRT_2PI * s2l;

        float zr[P_], wr[P_];
        #pragma unroll
        for (int c = 0; c < 4; ++c) {
            const float4 z4 = rp[40 + c], w4 = rp[44 + c];
            zr[4*c+0] = z4.x; zr[4*c+1] = z4.y; zr[4*c+2] = z4.z; zr[4*c+3] = z4.w;
            wr[4*c+0] = w4.x; wr[4*c+1] = w4.y; wr[4*c+2] = w4.z; wr[4*c+3] = w4.w;
        }

        f2 xm2, xv2;
        xm2.x = xm_s[ln][ii];       xm2.y = xm_s[ln + 64][ii];
        xv2.x = xv_s[ln][ii];       xv2.y = xv_s[ln + 64][ii];
        f2 v2 = xv2 + l2;
        f2 cc2, nh2;
        cc2.x = rsqrtf(v2.x) * INV_SQRT_2PI;
        cc2.y = rsqrtf(v2.y) * INV_SQRT_2PI;
        nh2.x = -0.5f / v2.x;
        nh2.y = -0.5f / v2.y;
        f2 dm2 = {0.f, 0.f};

        f2 u2[P_];
        int lk = 0;   // packed chunk index (static after unroll)
        #pragma unroll
        for (int m = 0; m < P_; ++m) {
            f2 d2 = xm2 - zr[m];
            f2 tt = d2 * d2 * nh2;
            f2 em2;
            em2.x = __expf(tt.x);
            em2.y = __expf(tt.y);
            dm2 += em2 * wr[m];

            const int c0 = m >> 2;
            #pragma unroll
            for (int c = c0; c < 4; ++c) {
                const float4 L4 = rp[lk];
                ++lk;
                if (m == 0) {
                    u2[4*c+0] = L4.x * em2;
                    u2[4*c+1] = L4.y * em2;
                    u2[4*c+2] = L4.z * em2;
                    u2[4*c+3] = L4.w * em2;
                } else {
                    u2[4*c+0] += L4.x * em2;
                    u2[4*c+1] += L4.y * em2;
                    u2[4*c+2] += L4.z * em2;
                    u2[4*c+3] += L4.w * em2;
                }
            }
        }

        f2 su2 = {0.f, 0.f};
        #pragma unroll
        for (int r = 0; r < P_; ++r) su2 += u2[r] * u2[r];

        am2 += cc2 * dm2;
        f2 t32;
        t32.x = s2l * rsqrtf(l2 + 2.f * xv2.x);
        t32.y = s2l * rsqrtf(l2 + 2.f * xv2.y);
        av2 += t32 - t4v * (cc2 * cc2) * su2;
    }

    atomicAdd(out + ln * O_ + o,                  am2.x);
    atomicAdd(out + (ln + 64) * O_ + o,           am2.y);
    atomicAdd(out + N_ * O_ + ln * O_ + o,        av2.x);
    atomicAdd(out + N_ * O_ + (ln + 64) * O_ + o, av2.y);
}

// ===================== Fallback: R5 monolithic kernel ======================
#define LSTR 20
__global__ __launch_bounds__(256, 2) void gp_fused(
    const float* __restrict__ x_mean, const float* __restrict__ x_var,
    const float* __restrict__ z_param, const float* __restrict__ h,
    const float* __restrict__ l_param, const float* __restrict__ s_param,
    const float* __restrict__ jitter_param, float* __restrict__ out)
{
    __shared__ float xm_s[N_][IT + 1];
    __shared__ float xv_s[N_][IT + 1];
    __shared__ __align__(16) float LinvT[ICH][OT][P_][LSTR];
    __shared__ __align__(16) float zS[ICH][OT][P_];
    __shared__ __align__(16) float wS[ICH][OT][P_];
    __shared__ float scS[ICH][OT][2];

    const int t = threadIdx.x;
    const int b = blockIdx.x;
    const int ot = b & 63;
    const int ir = b >> 6;
    const int o_base = ot * OT;
    const int i0 = ir * IT;

    {
        const int n = t >> 1, q = t & 1;
        const float4 xm4 = *(const float4*)(x_mean + n * I_ + i0 + q * 4);
        const float4 xv4 = *(const float4*)(x_var  + n * I_ + i0 + q * 4);
        xm_s[n][q*4+0] = xm4.x; xm_s[n][q*4+1] = xm4.y;
        xm_s[n][q*4+2] = xm4.z; xm_s[n][q*4+3] = xm4.w;
        xv_s[n][q*4+0] = xv4.x; xv_s[n][q*4+1] = xv4.y;
        xv_s[n][q*4+2] = xv4.z; xv_s[n][q*4+3] = xv4.w;
    }
    __syncthreads();

    f2 am2 = {0.f, 0.f};
    f2 av2 = {IT * 0.1f, IT * 0.1f};

    const int ol = t >> 6;
    const int ln = t & 63;
    const int g2 = t >> 4;
    const int il = g2 >> 2;
    const int g  = g2 & 3;
    const int p  = t & 15;

    for (int ii4 = 0; ii4 < IT / ICH; ++ii4) {
        {
            const int i  = i0 + ii4 * ICH + il;
            const int o  = o_base + g;
            const int io = i * O_ + o;
            const float l   = expf(l_param[io]) + 0.2f;
            const float s   = expf(s_param[io]) + 0.1f;
            const float jit = expf(jitter_param[io]) + 0.01f;
            const float l2 = l * l;
            const float inv2l2 = 0.5f / l2;
            const float cQ = INV_SQRT_2PI / l;
            const float noise = jit * jit / (s * s * l * SQRT_2PI);
            const float zp = tanhf(z_param[io * P_ + p]);

            float a[P_];
            #pragma unroll
            for (int c = 0; c < P_; ++c) {
                const float zc = __shfl(zp, c, P_);
                const float d = zp - zc;
                a[c] = cQ * __expf(-d * d * inv2l2) + ((c == p) ? noise : 0.0f);
            }
            #pragma unroll
            for (int k = 0; k < P_; ++k) {
                const float akk = __shfl(a[k], k, P_);
                const float lkk = sqrtf(akk);
                const float inv_lkk = 1.0f / lkk;
                if (p == k)      a[k] = lkk;
                else if (p > k)  a[k] *= inv_lkk;
                const float lrk = a[k];
                #pragma unroll
                for (int c = k + 1; c < P_; ++c) {
                    const float lck = __shfl(a[k], c, P_);
                    if (p >= c) a[c] -= lrk * lck;
                }
            }
            float x[P_];
            #pragma unroll
            for (int r = 0; r < P_; ++r) {
                const float lrr = __shfl(a[r], r, P_);
                float acc = (r == p) ? 1.0f : 0.0f;
                #pragma unroll
                for (int m = 0; m < r; ++m) {
                    const float lrm = __shfl(a[m], r, P_);
                    acc -= lrm * x[m];
                }
                x[r] = acc / lrr;
            }
            const float hc = h[io * P_ + p];
            float y[P_];
            #pragma unroll
            for (int r = 0; r < P_; ++r) y[r] = x[r] * hc;
            #pragma unroll
            for (int off = 8; off >= 1; off >>= 1) {
                #pragma unroll
                for (int r = 0; r < P_; ++r) y[r] += __shfl_xor(y[r], off, P_);
            }
            float wc = 0.f;
            #pragma unroll
            for (int r = 0; r < P_; ++r) wc += x[r] * y[r];

            float4* dst = (float4*)&LinvT[il][g][p][0];
            dst[0] = make_float4(x[ 0], x[ 1], x[ 2], x[ 3]);
            dst[1] = make_float4(x[ 4], x[ 5], x[ 6], x[ 7]);
            dst[2] = make_float4(x[ 8], x[ 9], x[10], x[11]);
            dst[3] = make_float4(x[12], x[13], x[14], x[15]);
            zS[il][g][p] = zp;
            wS[il][g][p] = wc;
            if (p == 0) { scS[il][g][0] = l2; scS[il][g][1] = s * s * l; }
        }
        __syncthreads();

        #pragma unroll
        for (int il2 = 0; il2 < ICH; ++il2) {
            const int iiA = ii4 * ICH + il2;
            const float l2  = scS[il2][ol][0];
            const float s2l = scS[il2][ol][1];
            const float t4v = SQRT_2PI * s2l;
            float zr[P_], wr[P_];
            {
                const float4* zp4 = (const float4*)&zS[il2][ol][0];
                const float4* wp4 = (const float4*)&wS[il2][ol][0];
                #pragma unroll
                for (int c = 0; c < 4; ++c) {
                    const float4 z4 = zp4[c], w4 = wp4[c];
                    zr[4*c+0] = z4.x; zr[4*c+1] = z4.y; zr[4*c+2] = z4.z; zr[4*c+3] = z4.w;
                    wr[4*c+0] = w4.x; wr[4*c+1] = w4.y; wr[4*c+2] = w4.z; wr[4*c+3] = w4.w;
                }
            }
            f2 xm2, xv2;
            xm2.x = xm_s[ln][iiA];       xm2.y = xm_s[ln + 64][iiA];
            xv2.x = xv_s[ln][iiA];       xv2.y = xv_s[ln + 64][iiA];
            f2 v2 = xv2 + l2;
            f2 cc2, nh2;
            cc2.x = rsqrtf(v2.x) * INV_SQRT_2PI;
            cc2.y = rsqrtf(v2.y) * INV_SQRT_2PI;
            nh2.x = -0.5f / v2.x;
            nh2.y = -0.5f / v2.y;
            f2 dm2 = {0.f, 0.f};
            f2 u2[P_];
            #pragma unroll
            for (int m = 0; m < P_; ++m) {
                f2 d2 = xm2 - zr[m];
                f2 tt = d2 * d2 * nh2;
                f2 em2;
                em2.x = __expf(tt.x);
                em2.y = __expf(tt.y);
                dm2 += em2 * wr[m];
                const int c0 = m >> 2;
                #pragma unroll
                for (int c = 0; c < 4; ++c) {
                    if (c < c0) continue;
                    const float4 L4 = *(const float4*)&LinvT[il2][ol][m][4*c];
                    if (m == 0) {
                        u2[4*c+0] = L4.x * em2;
                        u2[4*c+1] = L4.y * em2;
                        u2[4*c+2] = L4.z * em2;
                        u2[4*c+3] = L4.w * em2;
                    } else {
                        u2[4*c+0] += L4.x * em2;
                        u2[4*c+1] += L4.y * em2;
                        u2[4*c+2] += L4.z * em2;
                        u2[4*c+3] += L4.w * em2;
                    }
                }
            }
            f2 su2 = {0.f, 0.f};
            #pragma unroll
            for (int r = 0; r < P_; ++r) su2 += u2[r] * u2[r];
            am2 += cc2 * dm2;
            f2 t32;
            t32.x = s2l * rsqrtf(l2 + 2.f * xv2.x);
            t32.y = s2l * rsqrtf(l2 + 2.f * xv2.y);
            av2 += t32 - t4v * (cc2 * cc2) * su2;
        }
        __syncthreads();
    }

    const int o = o_base + ol;
    atomicAdd(out + ln * O_ + o,                  am2.x);
    atomicAdd(out + (ln + 64) * O_ + o,           am2.y);
    atomicAdd(out + N_ * O_ + ln * O_ + o,        av2.x);
    atomicAdd(out + N_ * O_ + (ln + 64) * O_ + o, av2.y);
}

extern "C" void kernel_launch(void* const* d_in, const int* in_sizes, int n_in,
                              void* d_out, int out_size, void* d_ws, size_t ws_size,
                              hipStream_t stream) {
    const float* x_mean = (const float*)d_in[0];
    const float* x_var  = (const float*)d_in[1];
    const float* z_param = (const float*)d_in[2];
    const float* h       = (const float*)d_in[3];
    const float* l_param = (const float*)d_in[4];
    const float* s_param = (const float*)d_in[5];
    const float* jitter_param = (const float*)d_in[6];
    float* out = (float*)d_out;

    hipMemsetAsync(d_out, 0, (size_t)out_size * sizeof(float), stream);
    if (ws_size >= NEED_BYTES) {
        gp_pairs<<<dim3(1024), dim3(64), 0, stream>>>(
            z_param, h, l_param, s_param, jitter_param, (float*)d_ws);
        gp_sites<<<dim3(2048), dim3(256), 0, stream>>>(
            x_mean, x_var, (const float*)d_ws, out);
    } else {
        gp_fused<<<dim3(2048), dim3(256), 0, stream>>>(
            x_mean, x_var, z_param, h, l_param, s_param, jitter_param, out);
    }
}